// Round 2
// baseline (3028.333 us; speedup 1.0000x reference)
//
#include <hip/hip_runtime.h>
#include <hip/hip_bf16.h>

// Problem constants (fixed by the harness).
#define N_B   128     // batch
#define L_SEQ 2048    // sequence length
#define H_DIM 256     // hidden
#define EMB   256     // embedding dim
#define G3    768     // 3 used gates (F, O, Htmp) * 256
#define G4    1024    // total gate rows
#define WROW  512     // W_w row length (H + Emb), C-order rows
#define V_SZ  32000   // vocab

// R14: r13 FAILED (absmax 5.8e-3 / raw 468) — pack/consume mapping was
// verified bitwise-equivalent to r12, so the failure is environmental: r13
// appended a 384KB Wpk buffer past Eg (ws 49.15->49.55MB) and lstm_rec read
// garbage weights beyond the valid workspace. r14 drops pack_w entirely
// (ws layout = r12's exactly) and restores r12's verbatim in-kernel weight
// load+convert (known-passing numerics).
// Perf model fix for r12's 2.8ms: WRITE_SIZE 6.5MB (no scratch spill) +
// FETCH 187MB (no HBM refetch) => weights re-loaded from L2 EVERY STEP:
// 512thr*768B*128blk*2048steps ~= 100GB / 2.8ms ~= 36 TB/s = the L2
// ceiling. Allocator budgeted 128 VGPRs (4 waves/EU target; launch_bounds'
// 2nd arg is only a floor). Fix: amdgpu_waves_per_eu(2,2) pins the target
// to 2 waves/EU (256-VGPR budget, always satisfiable for 8-wave blocks) +
// asm-fence the 192 weight dwords so the loads cannot be remat'd/sunk.

typedef unsigned short ushort_t;
typedef unsigned int   uint_t;

using f32x4  = __attribute__((ext_vector_type(4))) float;
using bf16x8 = __attribute__((ext_vector_type(8))) short;
using h2_t   = __attribute__((ext_vector_type(2))) _Float16;
using ushort4_t = __attribute__((ext_vector_type(4))) ushort_t;

__device__ __forceinline__ float bf2f(ushort_t u) {
  union { uint_t u; float f; } x; x.u = ((uint_t)u) << 16; return x.f;
}
__device__ __forceinline__ ushort_t f2bf(float f) {  // RNE f32 -> bf16
  union { float f; uint_t u; } x; x.f = f;
  return (ushort_t)((x.u + 0x7fffu + ((x.u >> 16) & 1u)) >> 16);
}
__device__ __forceinline__ float rcp_f(float x) {
#if __has_builtin(__builtin_amdgcn_rcpf)
  return __builtin_amdgcn_rcpf(x);
#else
  return 1.0f / x;
#endif
}
__device__ __forceinline__ float clampf(float x, float lo, float hi) {
  return fminf(fmaxf(x, lo), hi);
}
__device__ __forceinline__ float sigmoid_f(float x) {
  x = clampf(x, -30.f, 30.f);
  return rcp_f(1.0f + __expf(-x));
}
__device__ __forceinline__ float tanh_f(float x) {
  x = clampf(x, -15.f, 15.f);   // exact: tanh saturates well before 15
  float e = __expf(-2.0f * x);
  return (1.0f - e) * rcp_f(1.0f + e);
}
__device__ __forceinline__ float fdot2_f(h2_t a, h2_t b, float c) {
#if __has_builtin(__builtin_amdgcn_fdot2)
  return __builtin_amdgcn_fdot2(a, b, c, false);
#else
  return c + (float)a.x * (float)b.x + (float)a.y * (float)b.y;
#endif
}
__device__ __forceinline__ uint_t lane_bcast(uint_t v, int l) {
#if __has_builtin(__builtin_amdgcn_readlane)
  return (uint_t)__builtin_amdgcn_readlane((int)v, l);
#else
  return (uint_t)__shfl((int)v, l, 64);
#endif
}
// bf16 pair (packed dword, little-endian) -> f16 pair (exact for normal range)
__device__ __forceinline__ h2_t bfpair_to_h2(uint_t u) {
  union { uint_t u; float f; } lo, hi;
  lo.u = u << 16;
  hi.u = u & 0xffff0000u;
  h2_t r; r.x = (_Float16)lo.f; r.y = (_Float16)hi.f; return r;
}

// gate col g in [0,768) -> W_w row: F=g, O=512+(g-256), T=768+(g-512)
__device__ __forceinline__ int gmap(int g) { return (g < 256) ? g : g + 256; }

// ---------------------------------------------------------------------------
// Phase 0: dtype probe (validated: r11/r12 passed using these flags).
// ---------------------------------------------------------------------------
__global__ void dtype_probe(const uint_t* __restrict__ Ed,
                            const uint_t* __restrict__ Xd,
                            const uint_t* __restrict__ Wd,
                            uint_t* __restrict__ flags) {
  if (threadIdx.x != 0 || blockIdx.x != 0) return;
  int saneE = 0, saneW = 0;
  for (int i = 0; i < 256; ++i) {
    uint_t le = Ed[i] & 0xffffu, ee = (le >> 7) & 0xffu;
    if (ee == 0u || (ee >= 90u && ee <= 126u)) saneE++;
    uint_t lw = Wd[i] & 0xffffu, ew = (lw >> 7) & 0xffu;
    if (ew == 0u || (ew >= 90u && ew <= 126u)) saneW++;
  }
  uint_t nz = 0u;
  for (int i = 0; i < 128; ++i) nz |= Xd[2 * i + 1];
  flags[0] = (saneE < 192) ? 1u : 0u;   // 1 = f32
  flags[1] = (nz == 0u) ? 1u : 0u;      // 1 = int64
  flags[2] = (saneW < 192) ? 1u : 0u;   // 1 = f32
}

// ---------------------------------------------------------------------------
// Phase 1: Eg[v, g] = sum_k E[v,k] * W_w[gmap(g), 256+k] + W_b[gmap(g)]
// (unchanged from r11 — verified end-to-end, ~tens of µs)
// ---------------------------------------------------------------------------
__global__ __launch_bounds__(256) void eg_gemm(const void* __restrict__ Ein,
                                               const void* __restrict__ Wwin,
                                               const void* __restrict__ Wbin,
                                               _Float16* __restrict__ Eg,
                                               const uint_t* __restrict__ flags) {
  __shared__ __align__(16) ushort_t At[16][264];  // 16 x (256+8 pad) bf16
  const int tid = threadIdx.x;
  const int v0  = blockIdx.x * 16;
  const uint_t ef32 = flags[0];
  const uint_t wf32 = flags[2];

  if (!ef32) {
    const ushort_t* E = (const ushort_t*)Ein;
#pragma unroll
    for (int i = 0; i < 2; ++i) {
      int idx = tid + i * 256;           // 0..511
      int row = idx >> 5, seg = idx & 31;
      const uint4* src = (const uint4*)(E + (size_t)(v0 + row) * EMB + seg * 8);
      *(uint4*)&At[row][seg * 8] = *src;
    }
  } else {
    const float* Ef = (const float*)Ein;
#pragma unroll
    for (int i = 0; i < 4; ++i) {
      int idx = tid + i * 256;           // 0..1023
      int row = idx >> 6, seg = idx & 63;
      float4 v = *(const float4*)(Ef + (size_t)(v0 + row) * EMB + seg * 4);
      ushort4_t s;
      s.x = f2bf(v.x); s.y = f2bf(v.y); s.z = f2bf(v.z); s.w = f2bf(v.w);
      *(ushort4_t*)&At[row][seg * 4] = s;
    }
  }
  __syncthreads();

  const int lane = tid & 63, wv = tid >> 6;
  const int m = lane & 15, q = lane >> 4;

  f32x4 acc[12];
#pragma unroll
  for (int nt = 0; nt < 12; ++nt) acc[nt] = f32x4{0.f, 0.f, 0.f, 0.f};

  if (!wf32) {
    const ushort_t* Ww = (const ushort_t*)Wwin;
#pragma unroll
    for (int kt = 0; kt < 8; ++kt) {
      bf16x8 a = *(const bf16x8*)&At[m][kt * 32 + q * 8];
#pragma unroll
      for (int nt = 0; nt < 12; ++nt) {
        int g  = wv * 192 + nt * 16 + m;
        int gr = gmap(g);
        const bf16x8* bp =
            (const bf16x8*)(Ww + (size_t)gr * WROW + EMB + kt * 32 + q * 8);
        acc[nt] = __builtin_amdgcn_mfma_f32_16x16x32_bf16(a, *bp, acc[nt], 0, 0, 0);
      }
    }
  } else {
    const float* Wf = (const float*)Wwin;
#pragma unroll
    for (int kt = 0; kt < 8; ++kt) {
      bf16x8 a = *(const bf16x8*)&At[m][kt * 32 + q * 8];
#pragma unroll
      for (int nt = 0; nt < 12; ++nt) {
        int g  = wv * 192 + nt * 16 + m;
        int gr = gmap(g);
        const float* wp = Wf + (size_t)gr * WROW + EMB + kt * 32 + q * 8;
        float4 w0 = *(const float4*)(wp);
        float4 w1 = *(const float4*)(wp + 4);
        bf16x8 b;
        b[0] = (short)f2bf(w0.x); b[1] = (short)f2bf(w0.y);
        b[2] = (short)f2bf(w0.z); b[3] = (short)f2bf(w0.w);
        b[4] = (short)f2bf(w1.x); b[5] = (short)f2bf(w1.y);
        b[6] = (short)f2bf(w1.z); b[7] = (short)f2bf(w1.w);
        acc[nt] = __builtin_amdgcn_mfma_f32_16x16x32_bf16(a, b, acc[nt], 0, 0, 0);
      }
    }
  }

#pragma unroll
  for (int nt = 0; nt < 12; ++nt) {
    int g  = wv * 192 + nt * 16 + m;
    int gr = gmap(g);
    float bias = wf32 ? ((const float*)Wbin)[gr] : bf2f(((const ushort_t*)Wbin)[gr]);
#pragma unroll
    for (int j = 0; j < 4; ++j) {
      int v = v0 + q * 4 + j;
      Eg[(size_t)v * G3 + g] = (_Float16)(acc[nt][j] + bias);
    }
  }
}

// ---------------------------------------------------------------------------
// Phase 2 (R14): recurrence, 512 threads/block. R12's exact K-split and
// numerics (half = tid>>8 owns cols half*128:half*128+128 of rows
// {j,512+j,768+j}; weights loaded+converted ONCE from Wwin, dual dtype).
// New vs r12: occupancy pinned to 2 waves/EU (256-VGPR budget) and the 192
// weight dwords asm-fenced so the compiler cannot remat/sink the loads into
// the t-loop (r12's VGPR_Count=128 => per-step L2 refetch at the 36 TB/s
// L2 ceiling = the 2.8ms).
// ---------------------------------------------------------------------------
__global__
__attribute__((amdgpu_flat_work_group_size(512, 512), amdgpu_waves_per_eu(2, 2)))
void lstm_rec(const int* __restrict__ Xi,
              const void* __restrict__ Wwin,
              const _Float16* __restrict__ Eg,
              float* __restrict__ out,
              const uint_t* __restrict__ flags) {
  __shared__ uint_t hbuf[2][128];
  __shared__ float  pbuf[G3];
  const int tid  = threadIdx.x;          // 0..511
  const int lane = tid & 63;
  const int half = tid >> 8;             // 0 or 1 (wave-uniform)
  const int j    = tid & 255;            // hidden column
  const int n    = blockIdx.x;
  const uint_t wf32 = flags[2];
  const uint_t x64  = flags[1];

  // 192 weight dwords per thread (64 per gate), cols half*128 : half*128+128.
  // Stored as packed f16 pairs in uint dwords; MUST stay in VGPRs.
  uint_t wF[64], wO[64], wT[64];
  if (!wf32) {
    const uint_t* rF = (const uint_t*)((const ushort_t*)Wwin + (size_t)(j)       * WROW + half * 128);
    const uint_t* rO = (const uint_t*)((const ushort_t*)Wwin + (size_t)(512 + j) * WROW + half * 128);
    const uint_t* rT = (const uint_t*)((const ushort_t*)Wwin + (size_t)(768 + j) * WROW + half * 128);
#pragma unroll
    for (int d = 0; d < 64; ++d) {
      wF[d] = __builtin_bit_cast(uint_t, bfpair_to_h2(rF[d]));
      wO[d] = __builtin_bit_cast(uint_t, bfpair_to_h2(rO[d]));
      wT[d] = __builtin_bit_cast(uint_t, bfpair_to_h2(rT[d]));
    }
  } else {
    const float* rF = (const float*)Wwin + (size_t)(j)       * WROW + half * 128;
    const float* rO = (const float*)Wwin + (size_t)(512 + j) * WROW + half * 128;
    const float* rT = (const float*)Wwin + (size_t)(768 + j) * WROW + half * 128;
#pragma unroll
    for (int d = 0; d < 64; ++d) {
      float2 vF = *(const float2*)(rF + 2 * d);
      float2 vO = *(const float2*)(rO + 2 * d);
      float2 vT = *(const float2*)(rT + 2 * d);
      h2_t f, o, t2;
      f.x  = (_Float16)vF.x; f.y  = (_Float16)vF.y;
      o.x  = (_Float16)vO.x; o.y  = (_Float16)vO.y;
      t2.x = (_Float16)vT.x; t2.y = (_Float16)vT.y;
      wF[d] = __builtin_bit_cast(uint_t, f);
      wO[d] = __builtin_bit_cast(uint_t, o);
      wT[d] = __builtin_bit_cast(uint_t, t2);
    }
  }
  // Opacity fence: each weight dword becomes an opaque register value.
  // The compiler can no longer rematerialize it from Wwin inside the t-loop
  // (r12's failure mode). Under the 256-VGPR budget these stay resident.
#pragma unroll
  for (int d = 0; d < 64; ++d) {
    asm volatile("" : "+v"(wF[d]), "+v"(wO[d]), "+v"(wT[d]));
  }

  if (tid < 128) hbuf[0][tid] = 0u;  // h_0 = 0

  float c = 0.f, hlast = 0.f;
  const size_t xbase = (size_t)n * L_SEQ;

  // px(t=0), half-0 only (wave-uniform branch).
  float pxF = 0.f, pxO = 0.f, pxT = 0.f;
  if (half == 0) {
    int tok0 = x64 ? Xi[xbase * 2] : Xi[xbase];
    if ((uint_t)tok0 >= (uint_t)V_SZ) tok0 = 0;
    const _Float16* e = Eg + (size_t)tok0 * G3 + j;
    pxF = (float)e[0]; pxO = (float)e[256]; pxT = (float)e[512];
  }

  int cur = 0;
  for (int t = 0; t < L_SEQ; ++t) {
    __syncthreads();  // h(t) in hbuf[cur] published; pbuf free for this step

    const uint_t hv = hbuf[cur][half * 64 + lane];  // my half's h dwords

    // Prefetch px(t+1) (half-0), hidden behind the dot phase.
    float nF = 0.f, nO = 0.f, nT = 0.f;
    if (half == 0) {
      int tp = (t + 1 < L_SEQ) ? (t + 1) : (L_SEQ - 1);
      int tok = x64 ? Xi[(xbase + tp) * 2] : Xi[xbase + tp];
      if ((uint_t)tok >= (uint_t)V_SZ) tok = 0;
      const _Float16* e = Eg + (size_t)tok * G3 + j;
      nF = (float)e[0]; nO = (float)e[256]; nT = (float)e[512];
    }

    float aF0 = 0.f, aO0 = 0.f, aT0 = 0.f;
    float aF1 = 0.f, aO1 = 0.f, aT1 = 0.f;
#pragma unroll
    for (int d = 0; d < 64; ++d) {
      h2_t hh = __builtin_bit_cast(h2_t, lane_bcast(hv, d));
      h2_t wf = __builtin_bit_cast(h2_t, wF[d]);
      h2_t wo = __builtin_bit_cast(h2_t, wO[d]);
      h2_t wt = __builtin_bit_cast(h2_t, wT[d]);
      if (d & 1) {
        aF1 = fdot2_f(wf, hh, aF1);
        aO1 = fdot2_f(wo, hh, aO1);
        aT1 = fdot2_f(wt, hh, aT1);
      } else {
        aF0 = fdot2_f(wf, hh, aF0);
        aO0 = fdot2_f(wo, hh, aO0);
        aT0 = fdot2_f(wt, hh, aT0);
      }
    }
    float aF = aF0 + aF1, aO = aO0 + aO1, aT = aT0 + aT1;

    if (half == 1) {
      pbuf[j]       = aF;
      pbuf[256 + j] = aO;
      pbuf[512 + j] = aT;
    }
    __syncthreads();  // partials ready

    if (half == 0) {
      aF += pbuf[j]       + pxF;
      aO += pbuf[256 + j] + pxO;
      aT += pbuf[512 + j] + pxT;
      float Fg = sigmoid_f(aF);
      float Og = sigmoid_f(aO);
      float Tg = tanh_f(aT);
      c = Fg * c + Og * Tg;        // faithful to ref: uses O-gate, not I-gate
      float hv2 = Og * tanh_f(c);
      hlast = hv2;
      ((_Float16*)hbuf[cur ^ 1])[j] = (_Float16)hv2;  // publish h(t+1)
      pxF = nF; pxO = nO; pxT = nT;
    }
    cur ^= 1;
  }

  // FLOAT32 output, C-order (n, j).
  if (half == 0) out[(size_t)n * H_DIM + j] = hlast;
}

extern "C" void kernel_launch(void* const* d_in, const int* in_sizes, int n_in,
                              void* d_out, int out_size, void* d_ws, size_t ws_size,
                              hipStream_t stream) {
  const void* X  = d_in[0];
  const void* E  = d_in[1];
  const void* Ww = d_in[2];
  const void* Wb = d_in[3];
  for (int i = 0; i < n_in && i < 4; ++i) {
    switch (in_sizes[i]) {
      case N_B * L_SEQ: X  = d_in[i]; break;   // 262144
      case V_SZ * EMB:  E  = d_in[i]; break;   // 8192000
      case G4 * WROW:   Ww = d_in[i]; break;   // 524288
      case G4:          Wb = d_in[i]; break;   // 1024
      default: break;
    }
  }
  float* out = (float*)d_out;

  // ws: [0,256) flags | [256, ...) Eg (32000*768 f16 = 46.9 MiB). (= r12)
  uint_t*   flags = (uint_t*)d_ws;
  _Float16* Eg    = (_Float16*)((char*)d_ws + 256);

  dtype_probe<<<dim3(1), dim3(64), 0, stream>>>(
      (const uint_t*)E, (const uint_t*)X, (const uint_t*)Ww, flags);
  eg_gemm<<<dim3(V_SZ / 16), dim3(256), 0, stream>>>(E, Ww, Wb, Eg, flags);
  lstm_rec<<<dim3(N_B), dim3(512), 0, stream>>>((const int*)X, Ww, Eg, out, flags);
}

// Round 3
// 3002.617 us; speedup vs baseline: 1.0086x; 1.0086x over previous
//
#include <hip/hip_runtime.h>
#include <hip/hip_bf16.h>

// Problem constants (fixed by the harness).
#define N_B   128     // batch
#define L_SEQ 2048    // sequence length
#define H_DIM 256     // hidden
#define EMB   256     // embedding dim
#define G3    768     // 3 used gates (F, O, Htmp) * 256
#define G4    1024    // total gate rows
#define WROW  512     // W_w row length (H + Emb), C-order rows
#define V_SZ  32000   // vocab

// R15: r14 was byte-identical to r12 (dur 2820us, VGPR 128, FETCH 187.55MB
// to the KB) — neither waves_per_eu(2,2) nor the asm fence changed the
// loop. Root cause: 192 live dwords/thread can NEVER fit the 128-VGPR
// budget and HIP-level attributes don't force a 256-budget plan; the
// allocator either re-fetches W per step (L2) or round-trips AGPRs —
// either way ~600 ops/wave/step vs ~280 needed, 3300 cy/step measured.
// Fix: restructure so residency FITS 128: 1024-thread block (16 waves ->
// hardware VGPR cap IS 128, compiler must target it), 4-way K-split ->
// 96 weight dwords + ~25 scalars per thread. Dot = 96 fdot2 + 32 readlane.
// Quarters 1-3 write partials to LDS; quarter 0 reduces + epilogue.

typedef unsigned short ushort_t;
typedef unsigned int   uint_t;

using f32x4  = __attribute__((ext_vector_type(4))) float;
using bf16x8 = __attribute__((ext_vector_type(8))) short;
using h2_t   = __attribute__((ext_vector_type(2))) _Float16;
using ushort4_t = __attribute__((ext_vector_type(4))) ushort_t;
using u32x4  = __attribute__((ext_vector_type(4))) uint_t;

__device__ __forceinline__ float bf2f(ushort_t u) {
  union { uint_t u; float f; } x; x.u = ((uint_t)u) << 16; return x.f;
}
__device__ __forceinline__ ushort_t f2bf(float f) {  // RNE f32 -> bf16
  union { float f; uint_t u; } x; x.f = f;
  return (ushort_t)((x.u + 0x7fffu + ((x.u >> 16) & 1u)) >> 16);
}
__device__ __forceinline__ float rcp_f(float x) {
#if __has_builtin(__builtin_amdgcn_rcpf)
  return __builtin_amdgcn_rcpf(x);
#else
  return 1.0f / x;
#endif
}
__device__ __forceinline__ float clampf(float x, float lo, float hi) {
  return fminf(fmaxf(x, lo), hi);
}
__device__ __forceinline__ float sigmoid_f(float x) {
  x = clampf(x, -30.f, 30.f);
  return rcp_f(1.0f + __expf(-x));
}
__device__ __forceinline__ float tanh_f(float x) {
  x = clampf(x, -15.f, 15.f);   // exact: tanh saturates well before 15
  float e = __expf(-2.0f * x);
  return (1.0f - e) * rcp_f(1.0f + e);
}
__device__ __forceinline__ float fdot2_f(h2_t a, h2_t b, float c) {
#if __has_builtin(__builtin_amdgcn_fdot2)
  return __builtin_amdgcn_fdot2(a, b, c, false);
#else
  return c + (float)a.x * (float)b.x + (float)a.y * (float)b.y;
#endif
}
__device__ __forceinline__ uint_t lane_bcast(uint_t v, int l) {
#if __has_builtin(__builtin_amdgcn_readlane)
  return (uint_t)__builtin_amdgcn_readlane((int)v, l);
#else
  return (uint_t)__shfl((int)v, l, 64);
#endif
}
// bf16 pair (packed dword, little-endian) -> f16 pair (exact for normal range)
__device__ __forceinline__ h2_t bfpair_to_h2(uint_t u) {
  union { uint_t u; float f; } lo, hi;
  lo.u = u << 16;
  hi.u = u & 0xffff0000u;
  h2_t r; r.x = (_Float16)lo.f; r.y = (_Float16)hi.f; return r;
}

// gate col g in [0,768) -> W_w row: F=g, O=512+(g-256), T=768+(g-512)
__device__ __forceinline__ int gmap(int g) { return (g < 256) ? g : g + 256; }

// ---------------------------------------------------------------------------
// Phase 0: dtype probe (validated: r11/r12/r14 passed using these flags).
// ---------------------------------------------------------------------------
__global__ void dtype_probe(const uint_t* __restrict__ Ed,
                            const uint_t* __restrict__ Xd,
                            const uint_t* __restrict__ Wd,
                            uint_t* __restrict__ flags) {
  if (threadIdx.x != 0 || blockIdx.x != 0) return;
  int saneE = 0, saneW = 0;
  for (int i = 0; i < 256; ++i) {
    uint_t le = Ed[i] & 0xffffu, ee = (le >> 7) & 0xffu;
    if (ee == 0u || (ee >= 90u && ee <= 126u)) saneE++;
    uint_t lw = Wd[i] & 0xffffu, ew = (lw >> 7) & 0xffu;
    if (ew == 0u || (ew >= 90u && ew <= 126u)) saneW++;
  }
  uint_t nz = 0u;
  for (int i = 0; i < 128; ++i) nz |= Xd[2 * i + 1];
  flags[0] = (saneE < 192) ? 1u : 0u;   // 1 = f32
  flags[1] = (nz == 0u) ? 1u : 0u;      // 1 = int64
  flags[2] = (saneW < 192) ? 1u : 0u;   // 1 = f32
}

// ---------------------------------------------------------------------------
// Phase 1: Eg[v, g] = sum_k E[v,k] * W_w[gmap(g), 256+k] + W_b[gmap(g)]
// (unchanged from r11 — verified end-to-end, ~tens of µs)
// ---------------------------------------------------------------------------
__global__ __launch_bounds__(256) void eg_gemm(const void* __restrict__ Ein,
                                               const void* __restrict__ Wwin,
                                               const void* __restrict__ Wbin,
                                               _Float16* __restrict__ Eg,
                                               const uint_t* __restrict__ flags) {
  __shared__ __align__(16) ushort_t At[16][264];  // 16 x (256+8 pad) bf16
  const int tid = threadIdx.x;
  const int v0  = blockIdx.x * 16;
  const uint_t ef32 = flags[0];
  const uint_t wf32 = flags[2];

  if (!ef32) {
    const ushort_t* E = (const ushort_t*)Ein;
#pragma unroll
    for (int i = 0; i < 2; ++i) {
      int idx = tid + i * 256;           // 0..511
      int row = idx >> 5, seg = idx & 31;
      const uint4* src = (const uint4*)(E + (size_t)(v0 + row) * EMB + seg * 8);
      *(uint4*)&At[row][seg * 8] = *src;
    }
  } else {
    const float* Ef = (const float*)Ein;
#pragma unroll
    for (int i = 0; i < 4; ++i) {
      int idx = tid + i * 256;           // 0..1023
      int row = idx >> 6, seg = idx & 63;
      float4 v = *(const float4*)(Ef + (size_t)(v0 + row) * EMB + seg * 4);
      ushort4_t s;
      s.x = f2bf(v.x); s.y = f2bf(v.y); s.z = f2bf(v.z); s.w = f2bf(v.w);
      *(ushort4_t*)&At[row][seg * 4] = s;
    }
  }
  __syncthreads();

  const int lane = tid & 63, wv = tid >> 6;
  const int m = lane & 15, q = lane >> 4;

  f32x4 acc[12];
#pragma unroll
  for (int nt = 0; nt < 12; ++nt) acc[nt] = f32x4{0.f, 0.f, 0.f, 0.f};

  if (!wf32) {
    const ushort_t* Ww = (const ushort_t*)Wwin;
#pragma unroll
    for (int kt = 0; kt < 8; ++kt) {
      bf16x8 a = *(const bf16x8*)&At[m][kt * 32 + q * 8];
#pragma unroll
      for (int nt = 0; nt < 12; ++nt) {
        int g  = wv * 192 + nt * 16 + m;
        int gr = gmap(g);
        const bf16x8* bp =
            (const bf16x8*)(Ww + (size_t)gr * WROW + EMB + kt * 32 + q * 8);
        acc[nt] = __builtin_amdgcn_mfma_f32_16x16x32_bf16(a, *bp, acc[nt], 0, 0, 0);
      }
    }
  } else {
    const float* Wf = (const float*)Wwin;
#pragma unroll
    for (int kt = 0; kt < 8; ++kt) {
      bf16x8 a = *(const bf16x8*)&At[m][kt * 32 + q * 8];
#pragma unroll
      for (int nt = 0; nt < 12; ++nt) {
        int g  = wv * 192 + nt * 16 + m;
        int gr = gmap(g);
        const float* wp = Wf + (size_t)gr * WROW + EMB + kt * 32 + q * 8;
        float4 w0 = *(const float4*)(wp);
        float4 w1 = *(const float4*)(wp + 4);
        bf16x8 b;
        b[0] = (short)f2bf(w0.x); b[1] = (short)f2bf(w0.y);
        b[2] = (short)f2bf(w0.z); b[3] = (short)f2bf(w0.w);
        b[4] = (short)f2bf(w1.x); b[5] = (short)f2bf(w1.y);
        b[6] = (short)f2bf(w1.z); b[7] = (short)f2bf(w1.w);
        acc[nt] = __builtin_amdgcn_mfma_f32_16x16x32_bf16(a, b, acc[nt], 0, 0, 0);
      }
    }
  }

#pragma unroll
  for (int nt = 0; nt < 12; ++nt) {
    int g  = wv * 192 + nt * 16 + m;
    int gr = gmap(g);
    float bias = wf32 ? ((const float*)Wbin)[gr] : bf2f(((const ushort_t*)Wbin)[gr]);
#pragma unroll
    for (int j = 0; j < 4; ++j) {
      int v = v0 + q * 4 + j;
      Eg[(size_t)v * G3 + g] = (_Float16)(acc[nt][j] + bias);
    }
  }
}

// ---------------------------------------------------------------------------
// Phase 2 (R15): recurrence, 1024 threads/block, 4-way K-split.
// Thread (q4 = tid>>8, j = tid&255) owns cols q4*64 .. q4*64+63 of W rows
// {j, 512+j, 768+j}: w[0..31]=F, w[32..63]=O, w[64..95]=T (f16-pair dwords).
// 16-wave block -> hardware VGPR cap is 128; 96 weights + ~25 scalars fits,
// so residency is achievable within the budget the compiler MUST target.
// Dot: hv = hbuf dword (q4*32 + lane&31); readlane d gives h dword q4*32+d.
// Quarters 1..3 write partials to pbuf; quarter 0 reduces + gates + h.
// ---------------------------------------------------------------------------
__global__
__attribute__((amdgpu_flat_work_group_size(1024, 1024), amdgpu_waves_per_eu(4, 4)))
void lstm_rec(const int* __restrict__ Xi,
              const void* __restrict__ Wwin,
              const _Float16* __restrict__ Eg,
              float* __restrict__ out,
              const uint_t* __restrict__ flags) {
  __shared__ uint_t hbuf[2][128];
  __shared__ float  pbuf[3][G3];         // partials from q4 = 1,2,3 (9 KiB)
  const int tid  = threadIdx.x;          // 0..1023
  const int lane = tid & 63;
  const int q4   = tid >> 8;             // 0..3 (wave-uniform)
  const int j    = tid & 255;            // hidden column
  const int n    = blockIdx.x;
  const uint_t wf32 = flags[2];
  const uint_t x64  = flags[1];

  // 96 weight dwords per thread (32 per gate), cols q4*64 : q4*64+64.
  uint_t w[96];
  if (!wf32) {
    const ushort_t* Wb16 = (const ushort_t*)Wwin;
#pragma unroll
    for (int G = 0; G < 3; ++G) {
      const int row = (G == 0) ? j : ((G == 1) ? 512 + j : 768 + j);
      const u32x4* src = (const u32x4*)(Wb16 + (size_t)row * WROW + q4 * 64);
#pragma unroll
      for (int i = 0; i < 8; ++i) {
        u32x4 v = src[i];
#pragma unroll
        for (int cdw = 0; cdw < 4; ++cdw)
          w[G * 32 + i * 4 + cdw] = __builtin_bit_cast(uint_t, bfpair_to_h2(v[cdw]));
      }
    }
  } else {
    const float* Wf = (const float*)Wwin;
#pragma unroll
    for (int G = 0; G < 3; ++G) {
      const int row = (G == 0) ? j : ((G == 1) ? 512 + j : 768 + j);
      const float* src = Wf + (size_t)row * WROW + q4 * 64;
#pragma unroll
      for (int dd = 0; dd < 32; ++dd) {
        float2 v = *(const float2*)(src + 2 * dd);
        h2_t p; p.x = (_Float16)v.x; p.y = (_Float16)v.y;   // RNE, = r12
        w[G * 32 + dd] = __builtin_bit_cast(uint_t, p);
      }
    }
  }
  // Opacity fence: bias against load-sinking. With a feasible budget
  // (96+~25 <= 128) the allocator should keep these resident.
#pragma unroll
  for (int dd = 0; dd < 96; ++dd) asm volatile("" : "+v"(w[dd]));

  if (tid < 128) hbuf[0][tid] = 0u;  // h_0 = 0

  float c = 0.f, hlast = 0.f;
  const size_t xbase = (size_t)n * L_SEQ;

  // px(t=0), quarter-0 only (wave-uniform branch).
  float pxF = 0.f, pxO = 0.f, pxT = 0.f;
  if (q4 == 0) {
    int tok0 = x64 ? Xi[xbase * 2] : Xi[xbase];
    if ((uint_t)tok0 >= (uint_t)V_SZ) tok0 = 0;
    const _Float16* e = Eg + (size_t)tok0 * G3 + j;
    pxF = (float)e[0]; pxO = (float)e[256]; pxT = (float)e[512];
  }

  int cur = 0;
  for (int t = 0; t < L_SEQ; ++t) {
    __syncthreads();  // h(t) in hbuf[cur] published; pbuf free for this step

    const uint_t hv = hbuf[cur][q4 * 32 + (lane & 31)];  // my quarter's h dwords

    // Prefetch px(t+1) (quarter-0), hidden behind the dot phase.
    float nF = 0.f, nO = 0.f, nT = 0.f;
    if (q4 == 0) {
      int tp = (t + 1 < L_SEQ) ? (t + 1) : (L_SEQ - 1);
      int tok = x64 ? Xi[(xbase + tp) * 2] : Xi[xbase + tp];
      if ((uint_t)tok >= (uint_t)V_SZ) tok = 0;
      const _Float16* e = Eg + (size_t)tok * G3 + j;
      nF = (float)e[0]; nO = (float)e[256]; nT = (float)e[512];
    }

    float aF0 = 0.f, aO0 = 0.f, aT0 = 0.f;
    float aF1 = 0.f, aO1 = 0.f, aT1 = 0.f;
#pragma unroll
    for (int d = 0; d < 32; ++d) {
      h2_t hh = __builtin_bit_cast(h2_t, lane_bcast(hv, d));
      h2_t wf = __builtin_bit_cast(h2_t, w[d]);
      h2_t wo = __builtin_bit_cast(h2_t, w[32 + d]);
      h2_t wt = __builtin_bit_cast(h2_t, w[64 + d]);
      if (d & 1) {
        aF1 = fdot2_f(wf, hh, aF1);
        aO1 = fdot2_f(wo, hh, aO1);
        aT1 = fdot2_f(wt, hh, aT1);
      } else {
        aF0 = fdot2_f(wf, hh, aF0);
        aO0 = fdot2_f(wo, hh, aO0);
        aT0 = fdot2_f(wt, hh, aT0);
      }
    }
    float aF = aF0 + aF1, aO = aO0 + aO1, aT = aT0 + aT1;

    if (q4 != 0) {
      pbuf[q4 - 1][j]       = aF;
      pbuf[q4 - 1][256 + j] = aO;
      pbuf[q4 - 1][512 + j] = aT;
    }
    __syncthreads();  // partials ready

    if (q4 == 0) {
      aF += pbuf[0][j]       + pbuf[1][j]       + pbuf[2][j]       + pxF;
      aO += pbuf[0][256 + j] + pbuf[1][256 + j] + pbuf[2][256 + j] + pxO;
      aT += pbuf[0][512 + j] + pbuf[1][512 + j] + pbuf[2][512 + j] + pxT;
      float Fg = sigmoid_f(aF);
      float Og = sigmoid_f(aO);
      float Tg = tanh_f(aT);
      c = Fg * c + Og * Tg;        // faithful to ref: uses O-gate, not I-gate
      float hv2 = Og * tanh_f(c);
      hlast = hv2;
      ((_Float16*)hbuf[cur ^ 1])[j] = (_Float16)hv2;  // publish h(t+1)
      pxF = nF; pxO = nO; pxT = nT;
    }
    cur ^= 1;
  }

  // FLOAT32 output, C-order (n, j).
  if (q4 == 0) out[(size_t)n * H_DIM + j] = hlast;
}

extern "C" void kernel_launch(void* const* d_in, const int* in_sizes, int n_in,
                              void* d_out, int out_size, void* d_ws, size_t ws_size,
                              hipStream_t stream) {
  const void* X  = d_in[0];
  const void* E  = d_in[1];
  const void* Ww = d_in[2];
  const void* Wb = d_in[3];
  for (int i = 0; i < n_in && i < 4; ++i) {
    switch (in_sizes[i]) {
      case N_B * L_SEQ: X  = d_in[i]; break;   // 262144
      case V_SZ * EMB:  E  = d_in[i]; break;   // 8192000
      case G4 * WROW:   Ww = d_in[i]; break;   // 524288
      case G4:          Wb = d_in[i]; break;   // 1024
      default: break;
    }
  }
  float* out = (float*)d_out;

  // ws: [0,256) flags | [256, ...) Eg (32000*768 f16 = 46.9 MiB). (= r12)
  uint_t*   flags = (uint_t*)d_ws;
  _Float16* Eg    = (_Float16*)((char*)d_ws + 256);

  dtype_probe<<<dim3(1), dim3(64), 0, stream>>>(
      (const uint_t*)E, (const uint_t*)X, (const uint_t*)Ww, flags);
  eg_gemm<<<dim3(V_SZ / 16), dim3(256), 0, stream>>>(E, Ww, Wb, Eg, flags);
  lstm_rec<<<dim3(N_B), dim3(1024), 0, stream>>>((const int*)X, Ww, Eg, out, flags);
}